// Round 8
// baseline (25.295 us; speedup 1.0000x reference)
//
#include <hip/hip_runtime.h>

// Advection: out[b,i,j] = (s[b,min(i+1,H-1),j]-s[b,i,j])*v[b,i,j,0]
//                       + (s[b,i,min(j+1,W-1)]-s[b,i,j])*v[b,i,j,1]
// B=32, H=W=512, fp32. Persistent kernel: 512 WGs x 1024 thr = exactly
// 2 resident WGs/CU (32 waves), zero WG churn; 4 grid-stride iterations
// with 1-deep software prefetch. Per-instruction accesses 100% lane-
// contiguous (R7 layout: thread owns px pair in each 128-px half-wave chunk).

#define H 512
#define W 512
#define PLANE (H * W)            // 262144
#define TOTAL_PX (32 * PLANE)    // 8,388,608
#define NWG 512
#define BLK 1024
#define ITERS 4
#define STRIDE (NWG * BLK * 4)   // 2,097,152 px per iteration

typedef float f2 __attribute__((ext_vector_type(2)));
typedef float f4 __attribute__((ext_vector_type(4)));

struct PxLoads { f2 s0, sd; float s2; f4 v; };

__device__ __forceinline__ PxLoads load_pair(const float* __restrict__ s,
                                             const float* __restrict__ v, int p) {
    const int b   = p >> 18;
    const int rem = p & (PLANE - 1);
    const int i   = rem >> 9;
    const int j   = rem & (W - 1);
    const float* srow = s + (size_t)b * PLANE + (size_t)i * W;
    const float* srd  = srow + ((i + 1 < H) ? W : 0);
    PxLoads L;
    L.s0 = *reinterpret_cast<const f2*>(srow + j);
    L.sd = *reinterpret_cast<const f2*>(srd + j);
    L.s2 = srow[(j + 2 < W) ? j + 2 : W - 1];   // j even, <=510
    L.v  = *reinterpret_cast<const f4*>(v + (size_t)p * 2);
    return L;
}

__device__ __forceinline__ f2 compute(const PxLoads& L) {
    f2 o;
    o.x = (L.sd.x - L.s0.x) * L.v.x + (L.s0.y - L.s0.x) * L.v.y;
    o.y = (L.sd.y - L.s0.y) * L.v.z + (L.s2   - L.s0.y) * L.v.w;
    return o;
}

__global__ __launch_bounds__(BLK, 8) void advect_kernel(
    const float* __restrict__ s,
    const float* __restrict__ v,
    float* __restrict__ out)
{
    const int tid  = blockIdx.x * BLK + threadIdx.x;
    const int wav  = tid >> 6;
    const int lane = tid & 63;

    int pA = (wav << 8) + (lane << 1);   // 256 px per wave per iteration
    int pB = pA + 128;

    PxLoads A = load_pair(s, v, pA);
    PxLoads B = load_pair(s, v, pB);

    #pragma unroll
    for (int k = 0; k < ITERS; ++k) {
        PxLoads A2, B2;
        if (k + 1 < ITERS) {             // prefetch next iteration's loads
            A2 = load_pair(s, v, pA + STRIDE);
            B2 = load_pair(s, v, pB + STRIDE);
        }
        const f2 oA = compute(A);
        const f2 oB = compute(B);
        *reinterpret_cast<f2*>(out + pA) = oA;
        *reinterpret_cast<f2*>(out + pB) = oB;
        pA += STRIDE;
        pB += STRIDE;
        A = A2;
        B = B2;
    }
}

extern "C" void kernel_launch(void* const* d_in, const int* in_sizes, int n_in,
                              void* d_out, int out_size, void* d_ws, size_t ws_size,
                              hipStream_t stream) {
    const float* s = (const float*)d_in[0];   // [32,512,512,1] f32
    const float* v = (const float*)d_in[1];   // [32,512,512,2] f32
    float* out = (float*)d_out;               // [32,512,512,1] f32

    // TOTAL_PX = NWG*BLK*4*ITERS exactly
    advect_kernel<<<NWG, BLK, 0, stream>>>(s, v, out);
}

// Round 9
// 24.819 us; speedup vs baseline: 1.0192x; 1.0192x over previous
//
#include <hip/hip_runtime.h>

// Advection: out[b,i,j] = (s[b,min(i+1,H-1),j]-s[b,i,j])*v[b,i,j,0]
//                       + (s[b,i,min(j+1,W-1)]-s[b,i,j])*v[b,i,j,1]
// B=32, H=W=512, fp32. FINAL (best of 8 rounds, 24.75 us = 86% of the
// 6.29 TB/s copy ceiling on 134 MB compulsory traffic).
// Layout: every VMEM instruction 100% lane-contiguous. Each wave owns 256
// consecutive px (2 chunks of 128). Thread (lane l) owns px pair (2l,2l+1)
// in each chunk -> velocity float4 @16B/lane, state float2 @8B/lane,
// store float2 @8B/lane, all perfectly packed per instruction.
// Block=1024: full wave occupancy with only 2 resident WGs/CU (R6: +4%).

#define H 512
#define W 512
#define PLANE (H * W)   // 262144

typedef float f2 __attribute__((ext_vector_type(2)));
typedef float f4 __attribute__((ext_vector_type(4)));

__global__ __launch_bounds__(1024) void advect_kernel(
    const float* __restrict__ s,
    const float* __restrict__ v,
    float* __restrict__ out)
{
    const int lane = threadIdx.x & 63;
    const int gw   = blockIdx.x * (1024 / 64) + (threadIdx.x >> 6); // global wave
    const int base = gw << 8;                                      // 256 px/wave

    // ---- chunk A: px = base + 2*lane ----
    const int pA   = base + (lane << 1);
    const int bA   = pA >> 18;
    const int remA = pA & (PLANE - 1);
    const int iA   = remA >> 9;
    const int jA   = remA & (W - 1);
    const float* srowA   = s + (size_t)bA * PLANE + (size_t)iA * W;
    const float* srowdnA = srowA + ((iA + 1 < H) ? W : 0);

    // ---- chunk B: px = base + 128 + 2*lane ----
    const int pB   = pA + 128;
    const int bB   = pB >> 18;
    const int remB = pB & (PLANE - 1);
    const int iB   = remB >> 9;
    const int jB   = remB & (W - 1);
    const float* srowB   = s + (size_t)bB * PLANE + (size_t)iB * W;
    const float* srowdnB = srowB + ((iB + 1 < H) ? W : 0);

    // ---- issue all loads before any use ----
    const f2 s0A = *reinterpret_cast<const f2*>(srowA + jA);
    const f2 sdA = *reinterpret_cast<const f2*>(srowdnA + jA);
    const f2 s0B = *reinterpret_cast<const f2*>(srowB + jB);
    const f2 sdB = *reinterpret_cast<const f2*>(srowdnB + jB);
    // right neighbor of px jA+1 is jA+2, clamped to W-1 (j is even, <= 510)
    const float s2A = srowA[(jA + 2 < W) ? jA + 2 : W - 1];
    const float s2B = srowB[(jB + 2 < W) ? jB + 2 : W - 1];
    const f4 vA = *reinterpret_cast<const f4*>(v + (size_t)pA * 2);
    const f4 vB = *reinterpret_cast<const f4*>(v + (size_t)pB * 2);

    f2 oA, oB;
    oA.x = (sdA.x - s0A.x) * vA.x + (s0A.y - s0A.x) * vA.y;
    oA.y = (sdA.y - s0A.y) * vA.z + (s2A   - s0A.y) * vA.w;
    oB.x = (sdB.x - s0B.x) * vB.x + (s0B.y - s0B.x) * vB.y;
    oB.y = (sdB.y - s0B.y) * vB.z + (s2B   - s0B.y) * vB.w;

    *reinterpret_cast<f2*>(out + pA) = oA;
    *reinterpret_cast<f2*>(out + pB) = oB;
}

extern "C" void kernel_launch(void* const* d_in, const int* in_sizes, int n_in,
                              void* d_out, int out_size, void* d_ws, size_t ws_size,
                              hipStream_t stream) {
    const float* s = (const float*)d_in[0];   // [32,512,512,1] f32
    const float* v = (const float*)d_in[1];   // [32,512,512,2] f32
    float* out = (float*)d_out;               // [32,512,512,1] f32

    const int n_pixels = 32 * PLANE;          // 8,388,608
    const int block = 1024;
    const int px_per_block = 4 * block;       // 4096 (4 px/thread)
    const int grid = n_pixels / px_per_block; // 2048
    advect_kernel<<<grid, block, 0, stream>>>(s, v, out);
}